// Round 1
// baseline (528.154 us; speedup 1.0000x reference)
//
#include <hip/hip_runtime.h>

// Problem constants
#define NB 128       // batch (num_sims)
#define NA 64        // num_atoms
#define NE 4032      // edges = NA*(NA-1)
#define KT 2         // edge types
#define BE (NB * NE) // 516096 rows per edge type
// Output layout (floats): dv [128*64*32=262144] | de [128*4032*32=16515072] | zeros [128*4032*2=1032192]
#define DV_SIZE 262144
#define DE_SIZE 16515072
#define ZERO_SIZE 1032192

__device__ __forceinline__ float elu(float x) {
    return x > 0.0f ? x : __expf(x) - 1.0f;
}

// ---------------------------------------------------------------------------
// Kernel 1: agg[b,j,c] = (1/64) * sum_{i != j} e0[b, i, pos(i,j), c]
// pos(i,j) = j - (j > i). Pure gather; each e0 element read exactly once.
// ---------------------------------------------------------------------------
__global__ __launch_bounds__(256) void agg_kernel(const float* __restrict__ e0,
                                                  float* __restrict__ agg) {
    const int f = blockIdx.x * 256 + threadIdx.x;  // 262144 total
    const int c = f & 31;
    const int j = (f >> 5) & 63;
    const int b = f >> 11;
    float acc = 0.0f;
#pragma unroll 1
    for (int i = 0; i < 64; i++) {
        if (i == j) continue;
        const int p = j - (j > i ? 1 : 0);
        acc += e0[((b * 64 + i) * 63 + p) * 32 + c];
    }
    agg[f] = acc * (1.0f / 64.0f);
}

// ---------------------------------------------------------------------------
// Kernel 2: node MLP (32 -> 64 ELU -> 32 ELU), one thread per row (8192 rows),
// weights via wave-uniform indices (scalar loads). Also accumulates BN stats.
// ---------------------------------------------------------------------------
__global__ __launch_bounds__(256) void node_mlp_kernel(
    const float* __restrict__ agg, const float* __restrict__ W1,
    const float* __restrict__ b1, const float* __restrict__ W2,
    const float* __restrict__ b2, float* __restrict__ o_v,
    float* __restrict__ statv) {
    const int r = blockIdx.x * 256 + threadIdx.x;  // 8192 rows
    const float* x = agg + r * 32;

    float h[64];
#pragma unroll
    for (int hh = 0; hh < 64; hh++) h[hh] = b1[hh];

#pragma unroll 1
    for (int c4 = 0; c4 < 8; c4++) {
        const float4 xv = reinterpret_cast<const float4*>(x)[c4];
        const float* wr = W1 + c4 * 4 * 64;
#pragma unroll
        for (int hh = 0; hh < 64; hh++) {
            float a = h[hh];
            a = fmaf(xv.x, wr[hh], a);
            a = fmaf(xv.y, wr[64 + hh], a);
            a = fmaf(xv.z, wr[128 + hh], a);
            a = fmaf(xv.w, wr[192 + hh], a);
            h[hh] = a;
        }
    }
#pragma unroll
    for (int hh = 0; hh < 64; hh++) h[hh] = elu(h[hh]);

    float o[32];
#pragma unroll
    for (int c = 0; c < 32; c++) o[c] = b2[c];
#pragma unroll
    for (int hh = 0; hh < 64; hh++) {
        const float hv = h[hh];
        const float* wr = W2 + hh * 32;
#pragma unroll
        for (int c = 0; c < 32; c++) o[c] = fmaf(hv, wr[c], o[c]);
    }
#pragma unroll
    for (int c = 0; c < 32; c++) o[c] = elu(o[c]);

    float4* dst = reinterpret_cast<float4*>(o_v + r * 32);
#pragma unroll
    for (int q = 0; q < 8; q++)
        dst[q] = make_float4(o[q * 4], o[q * 4 + 1], o[q * 4 + 2], o[q * 4 + 3]);

    // BN stats: wave(64)-level butterfly reduce per channel, then one atomic/wave.
#pragma unroll
    for (int c = 0; c < 32; c++) {
        float s = o[c], ss = o[c] * o[c];
#pragma unroll
        for (int off = 32; off > 0; off >>= 1) {
            s += __shfl_down(s, off, 64);
            ss += __shfl_down(ss, off, 64);
        }
        if ((threadIdx.x & 63) == 0) {
            atomicAdd(&statv[c * 2], s);
            atomicAdd(&statv[c * 2 + 1], ss);
        }
    }
}

// ---------------------------------------------------------------------------
// Kernel 3: node BN normalize -> dv (d_out[0:262144])
// ---------------------------------------------------------------------------
__global__ __launch_bounds__(256) void node_norm_kernel(
    const float* __restrict__ o_v, const float* __restrict__ statv,
    const float* __restrict__ gamma, const float* __restrict__ beta,
    float* __restrict__ dv) {
    const int f = blockIdx.x * 256 + threadIdx.x;
    const int c = f & 31;
    const float M = 8192.0f;
    const float mu = statv[c * 2] / M;
    const float var = statv[c * 2 + 1] / M - mu * mu;
    const float rs = rsqrtf(var + 1e-5f);
    dv[f] = gamma[c] * (o_v[f] - mu) * rs + beta[c];
}

// ---------------------------------------------------------------------------
// Kernel 4: edge MLP (64 -> 64 ELU -> 32 ELU) for both types.
// One thread per (k, b, e) row; 4032 blocks (k uniform per block).
// ---------------------------------------------------------------------------
__global__ __launch_bounds__(256) void edge_mlp_kernel(
    const float* __restrict__ v0, const float* __restrict__ W1,
    const float* __restrict__ b1, const float* __restrict__ W2,
    const float* __restrict__ b2, float* __restrict__ o_e) {
    const int k = blockIdx.x / 2016;                       // uniform per block
    const int idx = (blockIdx.x % 2016) * 256 + threadIdx.x;  // b*E + e
    const int b = idx / NE;
    const int e = idx - b * NE;
    const int i = e / 63;                 // send (row)
    const int p = e - i * 63;
    const int j = p + (p >= i ? 1 : 0);   // recv (col)
    const float* xr = v0 + (b * NA + j) * 32;  // recv half first (concat order)
    const float* xs = v0 + (b * NA + i) * 32;
    const float* w1 = W1 + k * 64 * 64;
    const float* w2 = W2 + k * 64 * 32;

    float h[64];
#pragma unroll
    for (int hh = 0; hh < 64; hh++) h[hh] = b1[k * 64 + hh];

#pragma unroll 1
    for (int c4 = 0; c4 < 8; c4++) {
        const float4 xv = reinterpret_cast<const float4*>(xr)[c4];
        const float* wr = w1 + c4 * 4 * 64;
#pragma unroll
        for (int hh = 0; hh < 64; hh++) {
            float a = h[hh];
            a = fmaf(xv.x, wr[hh], a);
            a = fmaf(xv.y, wr[64 + hh], a);
            a = fmaf(xv.z, wr[128 + hh], a);
            a = fmaf(xv.w, wr[192 + hh], a);
            h[hh] = a;
        }
    }
#pragma unroll 1
    for (int c4 = 0; c4 < 8; c4++) {
        const float4 xv = reinterpret_cast<const float4*>(xs)[c4];
        const float* wr = w1 + 32 * 64 + c4 * 4 * 64;
#pragma unroll
        for (int hh = 0; hh < 64; hh++) {
            float a = h[hh];
            a = fmaf(xv.x, wr[hh], a);
            a = fmaf(xv.y, wr[64 + hh], a);
            a = fmaf(xv.z, wr[128 + hh], a);
            a = fmaf(xv.w, wr[192 + hh], a);
            h[hh] = a;
        }
    }
#pragma unroll
    for (int hh = 0; hh < 64; hh++) h[hh] = elu(h[hh]);

    float o[32];
#pragma unroll
    for (int c = 0; c < 32; c++) o[c] = b2[k * 32 + c];
#pragma unroll
    for (int hh = 0; hh < 64; hh++) {
        const float hv = h[hh];
        const float* wr = w2 + hh * 32;
#pragma unroll
        for (int c = 0; c < 32; c++) o[c] = fmaf(hv, wr[c], o[c]);
    }

    float4* dst = reinterpret_cast<float4*>(o_e + ((size_t)k * BE + (size_t)idx) * 32);
#pragma unroll
    for (int q = 0; q < 8; q++) {
        float4 v;
        v.x = elu(o[q * 4 + 0]);
        v.y = elu(o[q * 4 + 1]);
        v.z = elu(o[q * 4 + 2]);
        v.w = elu(o[q * 4 + 3]);
        dst[q] = v;
    }
}

// ---------------------------------------------------------------------------
// Kernel 5: edge BN stats pass over o_e -> 32-way bucketed partial sums
// ---------------------------------------------------------------------------
__global__ __launch_bounds__(256) void edge_stats_kernel(
    const float* __restrict__ o_e, float* __restrict__ buckets) {
    const int k = blockIdx.x >> 10;       // /1024, uniform
    const int blk = blockIdx.x & 1023;
    const int c = threadIdx.x & 31;
    const int g = threadIdx.x >> 5;       // 0..7
    const float* base = o_e + (size_t)k * BE * 32;
    float s = 0.0f, ss = 0.0f;
    int row = blk * 8 + g;
#pragma unroll 1
    for (int it = 0; it < 63; it++, row += 8192) {
        const float v = base[(size_t)row * 32 + c];
        s += v;
        ss += v * v;
    }
    __shared__ float red[256 * 2];
    red[threadIdx.x * 2] = s;
    red[threadIdx.x * 2 + 1] = ss;
    __syncthreads();
    if (threadIdx.x < 32) {
        float as = 0.0f, ass = 0.0f;
#pragma unroll
        for (int gg = 0; gg < 8; gg++) {
            as += red[(gg * 32 + c) * 2];
            ass += red[(gg * 32 + c) * 2 + 1];
        }
        const int bk = blockIdx.x & 31;
        atomicAdd(&buckets[((bk * KT + k) * 32 + c) * 2], as);
        atomicAdd(&buckets[((bk * KT + k) * 32 + c) * 2 + 1], ass);
    }
}

// ---------------------------------------------------------------------------
// Kernel 5b: finalize edge BN stats -> statf[(k*32+c)*2] = mu, +1 = rsqrt(var+eps)
// ---------------------------------------------------------------------------
__global__ void edge_stats_final_kernel(const float* __restrict__ buckets,
                                        float* __restrict__ statf) {
    const int t = threadIdx.x;
    if (t >= 64) return;
    const int k = t >> 5, c = t & 31;
    float s = 0.0f, ss = 0.0f;
#pragma unroll 1
    for (int bk = 0; bk < 32; bk++) {
        s += buckets[((bk * KT + k) * 32 + c) * 2];
        ss += buckets[((bk * KT + k) * 32 + c) * 2 + 1];
    }
    const float M = (float)BE;
    const float mu = s / M;
    const float var = ss / M - mu * mu;
    statf[(k * 32 + c) * 2] = mu;
    statf[(k * 32 + c) * 2 + 1] = rsqrtf(var + 1e-5f);
}

// ---------------------------------------------------------------------------
// Kernel 6: de[b,e,c] = sum_k edge_type[b,e,k] * (g_k(o_k - mu_k)rs_k + beta_k)
// float4 per thread over channels.
// ---------------------------------------------------------------------------
__global__ __launch_bounds__(256) void edge_out_kernel(
    const float* __restrict__ o_e, const float* __restrict__ etype,
    const float* __restrict__ statf, const float* __restrict__ gamma,
    const float* __restrict__ beta, float* __restrict__ de) {
    const int f = blockIdx.x * 256 + threadIdx.x;  // B*E*8
    const int q = f & 7;
    const int idx = f >> 3;
    const float w0 = etype[idx * 2];
    const float w1 = etype[idx * 2 + 1];
    const float4 v0q = reinterpret_cast<const float4*>(o_e)[(size_t)idx * 8 + q];
    const float4 v1q = reinterpret_cast<const float4*>(o_e)[((size_t)BE + idx) * 8 + q];
    const float a0[4] = {v0q.x, v0q.y, v0q.z, v0q.w};
    const float a1[4] = {v1q.x, v1q.y, v1q.z, v1q.w};
    float r[4];
    const int c0 = q * 4;
#pragma unroll
    for (int u = 0; u < 4; u++) {
        const int c = c0 + u;
        const float n0 = gamma[c] * (a0[u] - statf[c * 2]) * statf[c * 2 + 1] + beta[c];
        const float n1 =
            gamma[32 + c] * (a1[u] - statf[(32 + c) * 2]) * statf[(32 + c) * 2 + 1] +
            beta[32 + c];
        r[u] = n0 * w0 + n1 * w1;
    }
    reinterpret_cast<float4*>(de)[f] = make_float4(r[0], r[1], r[2], r[3]);
}

// ---------------------------------------------------------------------------
extern "C" void kernel_launch(void* const* d_in, const int* in_sizes, int n_in,
                              void* d_out, int out_size, void* d_ws, size_t ws_size,
                              hipStream_t stream) {
    const float* v0 = (const float*)d_in[0];
    const float* e0 = (const float*)d_in[1];
    const float* etype = (const float*)d_in[2];
    const float* W1v = (const float*)d_in[3];
    const float* b1v = (const float*)d_in[4];
    const float* W2v = (const float*)d_in[5];
    const float* b2v = (const float*)d_in[6];
    const float* gv = (const float*)d_in[7];
    const float* btv = (const float*)d_in[8];
    const float* W1e = (const float*)d_in[9];
    const float* b1e = (const float*)d_in[10];
    const float* W2e = (const float*)d_in[11];
    const float* b2e = (const float*)d_in[12];
    const float* ge = (const float*)d_in[13];
    const float* bte = (const float*)d_in[14];
    float* out = (float*)d_out;

    // Workspace layout (floats):
    float* ws = (float*)d_ws;
    float* agg = ws;                  // 262144
    float* o_v = ws + 262144;         // 262144
    float* statv = ws + 524288;       // 64
    float* buckets = ws + 524352;     // 4096
    float* statf = ws + 528448;       // 128
    float* o_e = ws + 528576;         // 33030144  (total ~134.2 MB)

    // Zero the stat accumulators (ws is poisoned 0xAA before every call)
    hipMemsetAsync(statv, 0, (64 + 4096) * sizeof(float), stream);
    // Output 3 is edge_type * 0 -> literal zeros
    hipMemsetAsync(out + DV_SIZE + DE_SIZE, 0, ZERO_SIZE * sizeof(float), stream);

    agg_kernel<<<1024, 256, 0, stream>>>(e0, agg);
    node_mlp_kernel<<<32, 256, 0, stream>>>(agg, W1v, b1v, W2v, b2v, o_v, statv);
    node_norm_kernel<<<1024, 256, 0, stream>>>(o_v, statv, gv, btv, out);
    edge_mlp_kernel<<<4032, 256, 0, stream>>>(v0, W1e, b1e, W2e, b2e, o_e);
    edge_stats_kernel<<<2048, 256, 0, stream>>>(o_e, buckets);
    edge_stats_final_kernel<<<1, 64, 0, stream>>>(buckets, statf);
    edge_out_kernel<<<16128, 256, 0, stream>>>(o_e, etype, statf, ge, bte, out + DV_SIZE);
}

// Round 2
// 384.777 us; speedup vs baseline: 1.3726x; 1.3726x over previous
//
#include <hip/hip_runtime.h>

// Problem constants
#define NB 128       // batch (num_sims)
#define NA 64        // num_atoms
#define NE 4032      // edges = NA*(NA-1)
#define KT 2         // edge types
#define BE (NB * NE) // 516096 rows per edge type
#define DV_SIZE 262144
#define DE_SIZE 16515072
#define ZERO_SIZE 1032192

#define TPW 8        // row-tiles (of 16 rows) per wave
#define PBLK 1008    // blocks for MFMA passes: 1008*4 waves*8 tiles*16 rows = 516096

typedef __attribute__((ext_vector_type(8))) short short8;
typedef __attribute__((ext_vector_type(4))) float floatx4;

__device__ __forceinline__ float elu(float x) {
    return x > 0.0f ? x : __expf(x) - 1.0f;
}

__device__ __forceinline__ unsigned short f2bf(float x) {
    unsigned u = __float_as_uint(x);
    return (unsigned short)((u + 0x7FFFu + ((u >> 16) & 1u)) >> 16);
}

__device__ __forceinline__ short8 pack8(float4 a, float4 b) {
    short8 r;
    r[0] = (short)f2bf(a.x); r[1] = (short)f2bf(a.y);
    r[2] = (short)f2bf(a.z); r[3] = (short)f2bf(a.w);
    r[4] = (short)f2bf(b.x); r[5] = (short)f2bf(b.y);
    r[6] = (short)f2bf(b.z); r[7] = (short)f2bf(b.w);
    return r;
}

// Shared-memory layout for the MFMA passes.
// A-operand fragments (weights, transposed) staged once per block.
// hbuf: per-wave 16-row x 64-hid bf16 tile, row stride 160 B (bank-spread, 16B-aligned).
struct SM {
    short8 wA1[16][64];            // GEMM1 A-frags: f = ((k*4+mt)*2+kf)   16 KB
    short8 wA2[8][64];             // GEMM2 A-frags: f = ((k*2+mt2)*2+kf)   8 KB
    float b1s[128];
    float b2s[64];
    float afs[64];                 // affine scale (pass B)
    float cfs[64];                 // affine shift (pass B)
    unsigned long long hbuf[4][16 * 20];  // 4 waves x 2560 B
};

// Stage weight fragments into LDS (cooperative, 256 threads). W1:(K,64,64) W2:(K,64,32)
__device__ __forceinline__ void stage_weights(SM& sm, const float* __restrict__ W1,
                                              const float* __restrict__ b1,
                                              const float* __restrict__ W2,
                                              const float* __restrict__ b2) {
    const int tid = threadIdx.x;
#pragma unroll
    for (int s = 0; s < 4; s++) {  // 16 frags x 64 lanes
        const int slot = s * 256 + tid;
        const int f = slot >> 6, l = slot & 63;
        const int k = f >> 3, mt = (f >> 1) & 3, kf = f & 1;
        const int g = l >> 4, m15 = l & 15;
        short8 v;
#pragma unroll
        for (int j = 0; j < 8; j++) {
            const int kk = kf * 32 + g * 8 + j;
            v[j] = (short)f2bf(W1[(k * 64 + kk) * 64 + mt * 16 + m15]);
        }
        sm.wA1[f][l] = v;
    }
#pragma unroll
    for (int s = 0; s < 2; s++) {  // 8 frags x 64 lanes
        const int slot = s * 256 + tid;
        const int f = slot >> 6, l = slot & 63;
        const int k = f >> 2, mt2 = (f >> 1) & 1, kf = f & 1;
        const int g = l >> 4, m15 = l & 15;
        short8 v;
#pragma unroll
        for (int j = 0; j < 8; j++) {
            const int kk = kf * 32 + g * 8 + j;
            v[j] = (short)f2bf(W2[(k * 64 + kk) * 32 + mt2 * 16 + m15]);
        }
        sm.wA2[f][l] = v;
    }
    if (tid < 128) sm.b1s[tid] = b1[tid];
    if (tid < 64) sm.b2s[tid] = b2[tid];
}

// Compute one 16-row tile of the edge MLP for both k types.
// o[k][mt2][r] = O value at edge-row (R0 + lane&15), channel mt2*16 + 4*(lane>>4) + r
__device__ __forceinline__ void mlp_tile(const SM& sm, int w, int lane,
                                         const float* __restrict__ v0, int R0,
                                         float o[2][2][4]) {
    const int g = lane >> 4, m15 = lane & 15;
    const int row = R0 + m15;
    const int b = row / NE;
    const int e = row - b * NE;
    const int i = e / 63;
    const int p = e - i * 63;
    const int j = p + (p >= i ? 1 : 0);
    // X^T B-fragments: kf0 = v0[b,j] (recv), kf1 = v0[b,i] (send); 8 consecutive ch per lane
    const float4* pr = (const float4*)(v0 + (b * 64 + j) * 32 + g * 8);
    const float4* ps = (const float4*)(v0 + (b * 64 + i) * 32 + g * 8);
    const short8 bx0 = pack8(pr[0], pr[1]);
    const short8 bx1 = pack8(ps[0], ps[1]);

    const char* hbase = (const char*)&sm.hbuf[w][0];
    unsigned long long* hw = const_cast<unsigned long long*>(&sm.hbuf[w][0]);

#pragma unroll
    for (int k = 0; k < 2; k++) {
        // GEMM1: H^T[hid][row] tile; C layout: col=lane&15 (row), m=hid=16mt+4g+r
#pragma unroll
        for (int mt = 0; mt < 4; mt++) {
            floatx4 acc = {0.f, 0.f, 0.f, 0.f};
            acc = __builtin_amdgcn_mfma_f32_16x16x32_bf16(sm.wA1[(k * 4 + mt) * 2 + 0][lane], bx0, acc, 0, 0, 0);
            acc = __builtin_amdgcn_mfma_f32_16x16x32_bf16(sm.wA1[(k * 4 + mt) * 2 + 1][lane], bx1, acc, 0, 0, 0);
            const float4 bb = *(const float4*)&sm.b1s[k * 64 + mt * 16 + 4 * g];
            const unsigned lo = (unsigned)f2bf(elu(acc[0] + bb.x)) |
                                ((unsigned)f2bf(elu(acc[1] + bb.y)) << 16);
            const unsigned hi = (unsigned)f2bf(elu(acc[2] + bb.z)) |
                                ((unsigned)f2bf(elu(acc[3] + bb.w)) << 16);
            // H stored [row m15][hid], row stride 160 B; ull idx = m15*20 + mt*4 + g
            hw[m15 * 20 + mt * 4 + g] = ((unsigned long long)hi << 32) | lo;
        }
        // GEMM2 B-frags: lane holds row=m15, hid = kf*32 + 8g..+7 (16 B contiguous)
        const short8 bh0 = *(const short8*)(hbase + m15 * 160 + 0 + g * 16);
        const short8 bh1 = *(const short8*)(hbase + m15 * 160 + 64 + g * 16);
#pragma unroll
        for (int mt2 = 0; mt2 < 2; mt2++) {
            floatx4 acc = {0.f, 0.f, 0.f, 0.f};
            acc = __builtin_amdgcn_mfma_f32_16x16x32_bf16(sm.wA2[(k * 2 + mt2) * 2 + 0][lane], bh0, acc, 0, 0, 0);
            acc = __builtin_amdgcn_mfma_f32_16x16x32_bf16(sm.wA2[(k * 2 + mt2) * 2 + 1][lane], bh1, acc, 0, 0, 0);
            const float4 bb = *(const float4*)&sm.b2s[k * 32 + mt2 * 16 + 4 * g];
            o[k][mt2][0] = elu(acc[0] + bb.x);
            o[k][mt2][1] = elu(acc[1] + bb.y);
            o[k][mt2][2] = elu(acc[2] + bb.z);
            o[k][mt2][3] = elu(acc[3] + bb.w);
        }
    }
}

// ---------------------------------------------------------------------------
// Pass A: edge MLP -> BN sum/sumsq per (k, ch), bucketed atomics (32 buckets)
// ---------------------------------------------------------------------------
__global__ __launch_bounds__(256) void edge_stats_mfma_kernel(
    const float* __restrict__ v0, const float* __restrict__ W1,
    const float* __restrict__ b1, const float* __restrict__ W2,
    const float* __restrict__ b2, float* __restrict__ buckets) {
    __shared__ SM sm;
    stage_weights(sm, W1, b1, W2, b2);
    __syncthreads();

    const int lane = threadIdx.x & 63;
    const int w = threadIdx.x >> 6;
    const int g = lane >> 4, m15 = lane & 15;
    const int gw = blockIdx.x * 4 + w;

    float st[2][2][4], sq[2][2][4];
#pragma unroll
    for (int k = 0; k < 2; k++)
#pragma unroll
        for (int m = 0; m < 2; m++)
#pragma unroll
            for (int r = 0; r < 4; r++) { st[k][m][r] = 0.f; sq[k][m][r] = 0.f; }

#pragma unroll 1
    for (int tt = 0; tt < TPW; tt++) {
        const int R0 = (gw * TPW + tt) * 16;
        float o[2][2][4];
        mlp_tile(sm, w, lane, v0, R0, o);
#pragma unroll
        for (int k = 0; k < 2; k++)
#pragma unroll
            for (int m = 0; m < 2; m++)
#pragma unroll
                for (int r = 0; r < 4; r++) {
                    const float v = o[k][m][r];
                    st[k][m][r] += v;
                    sq[k][m][r] += v * v;
                }
    }

    // reduce over the 16 row-lanes (low 4 lane bits), then 4 atomics-lanes/wave
    const int bk = gw & 31;
#pragma unroll
    for (int k = 0; k < 2; k++)
#pragma unroll
        for (int m = 0; m < 2; m++)
#pragma unroll
            for (int r = 0; r < 4; r++) {
                float s = st[k][m][r], ss = sq[k][m][r];
#pragma unroll
                for (int off = 1; off < 16; off <<= 1) {
                    s += __shfl_xor(s, off, 64);
                    ss += __shfl_xor(ss, off, 64);
                }
                if (m15 == 0) {
                    const int ch = m * 16 + 4 * g + r;
                    atomicAdd(&buckets[((bk * KT + k) * 32 + ch) * 2], s);
                    atomicAdd(&buckets[((bk * KT + k) * 32 + ch) * 2 + 1], ss);
                }
            }
}

// ---------------------------------------------------------------------------
// Finalize: fold BN into per-channel affine  af = gamma*rs, cf = beta - mu*af
// ---------------------------------------------------------------------------
__global__ void edge_stats_final_kernel(const float* __restrict__ buckets,
                                        const float* __restrict__ gamma,
                                        const float* __restrict__ beta,
                                        float* __restrict__ statf) {
    const int t = threadIdx.x;
    if (t >= 64) return;
    const int k = t >> 5, c = t & 31;
    float s = 0.0f, ss = 0.0f;
#pragma unroll 1
    for (int bk = 0; bk < 32; bk++) {
        s += buckets[((bk * KT + k) * 32 + c) * 2];
        ss += buckets[((bk * KT + k) * 32 + c) * 2 + 1];
    }
    const float M = (float)BE;
    const float mu = s / M;
    const float var = ss / M - mu * mu;
    const float rs = rsqrtf(var + 1e-5f);
    const float af = gamma[k * 32 + c] * rs;
    statf[t * 2] = af;
    statf[t * 2 + 1] = beta[k * 32 + c] - mu * af;
}

// ---------------------------------------------------------------------------
// Pass B: recompute edge MLP, apply affine + edge_type weighting, write de
// ---------------------------------------------------------------------------
__global__ __launch_bounds__(256) void edge_out_mfma_kernel(
    const float* __restrict__ v0, const float* __restrict__ W1,
    const float* __restrict__ b1, const float* __restrict__ W2,
    const float* __restrict__ b2, const float* __restrict__ statf,
    const float* __restrict__ etype, float* __restrict__ de) {
    __shared__ SM sm;
    stage_weights(sm, W1, b1, W2, b2);
    if (threadIdx.x < 64) {
        sm.afs[threadIdx.x] = statf[threadIdx.x * 2];
        sm.cfs[threadIdx.x] = statf[threadIdx.x * 2 + 1];
    }
    __syncthreads();

    const int lane = threadIdx.x & 63;
    const int w = threadIdx.x >> 6;
    const int g = lane >> 4, m15 = lane & 15;
    const int gw = blockIdx.x * 4 + w;

#pragma unroll 1
    for (int tt = 0; tt < TPW; tt++) {
        const int R0 = (gw * TPW + tt) * 16;
        float o[2][2][4];
        mlp_tile(sm, w, lane, v0, R0, o);
        const int row = R0 + m15;
        const float w0 = etype[row * 2 + 0];
        const float w1 = etype[row * 2 + 1];
#pragma unroll
        for (int mt2 = 0; mt2 < 2; mt2++) {
            const float4 a0 = *(const float4*)&sm.afs[mt2 * 16 + 4 * g];
            const float4 c0 = *(const float4*)&sm.cfs[mt2 * 16 + 4 * g];
            const float4 a1 = *(const float4*)&sm.afs[32 + mt2 * 16 + 4 * g];
            const float4 c1 = *(const float4*)&sm.cfs[32 + mt2 * 16 + 4 * g];
            float4 r;
            r.x = w0 * (a0.x * o[0][mt2][0] + c0.x) + w1 * (a1.x * o[1][mt2][0] + c1.x);
            r.y = w0 * (a0.y * o[0][mt2][1] + c0.y) + w1 * (a1.y * o[1][mt2][1] + c1.y);
            r.z = w0 * (a0.z * o[0][mt2][2] + c0.z) + w1 * (a1.z * o[1][mt2][2] + c1.z);
            r.w = w0 * (a0.w * o[0][mt2][3] + c0.w) + w1 * (a1.w * o[1][mt2][3] + c1.w);
            *(float4*)(de + (size_t)row * 32 + mt2 * 16 + 4 * g) = r;
        }
    }
}

// ---------------------------------------------------------------------------
// agg[b,j,c4] = (1/64) * sum_{i != j} e0[b, i, pos(i,j), c4]  (float4 per thread)
// ---------------------------------------------------------------------------
__global__ __launch_bounds__(256) void agg_kernel(const float* __restrict__ e0,
                                                  float* __restrict__ agg) {
    const int f = blockIdx.x * 256 + threadIdx.x;  // 65536 = B*N*8
    const int c4 = f & 7;
    const int jn = (f >> 3) & 63;
    const int b = f >> 9;
    const float4* base = (const float4*)e0 + (size_t)b * 64 * 63 * 8;
    float x = 0.f, y = 0.f, z = 0.f, ww = 0.f;
#pragma unroll 1
    for (int i = 0; i < 64; i++) {
        if (i == jn) continue;
        const int p = jn - (jn > i ? 1 : 0);
        const float4 v = base[(i * 63 + p) * 8 + c4];
        x += v.x; y += v.y; z += v.z; ww += v.w;
    }
    const float s = 1.0f / 64.0f;
    *(float4*)(agg + (size_t)f * 4) = make_float4(x * s, y * s, z * s, ww * s);
}

// ---------------------------------------------------------------------------
// Node MLP (32 -> 64 ELU -> 32 ELU) + BN stat accumulation (unchanged from R1)
// ---------------------------------------------------------------------------
__global__ __launch_bounds__(256) void node_mlp_kernel(
    const float* __restrict__ agg, const float* __restrict__ W1,
    const float* __restrict__ b1, const float* __restrict__ W2,
    const float* __restrict__ b2, float* __restrict__ o_v,
    float* __restrict__ statv) {
    const int r = blockIdx.x * 256 + threadIdx.x;  // 8192 rows
    const float* x = agg + r * 32;

    float h[64];
#pragma unroll
    for (int hh = 0; hh < 64; hh++) h[hh] = b1[hh];

#pragma unroll 1
    for (int c4 = 0; c4 < 8; c4++) {
        const float4 xv = reinterpret_cast<const float4*>(x)[c4];
        const float* wr = W1 + c4 * 4 * 64;
#pragma unroll
        for (int hh = 0; hh < 64; hh++) {
            float a = h[hh];
            a = fmaf(xv.x, wr[hh], a);
            a = fmaf(xv.y, wr[64 + hh], a);
            a = fmaf(xv.z, wr[128 + hh], a);
            a = fmaf(xv.w, wr[192 + hh], a);
            h[hh] = a;
        }
    }
#pragma unroll
    for (int hh = 0; hh < 64; hh++) h[hh] = elu(h[hh]);

    float o[32];
#pragma unroll
    for (int c = 0; c < 32; c++) o[c] = b2[c];
#pragma unroll
    for (int hh = 0; hh < 64; hh++) {
        const float hv = h[hh];
        const float* wr = W2 + hh * 32;
#pragma unroll
        for (int c = 0; c < 32; c++) o[c] = fmaf(hv, wr[c], o[c]);
    }
#pragma unroll
    for (int c = 0; c < 32; c++) o[c] = elu(o[c]);

    float4* dst = reinterpret_cast<float4*>(o_v + r * 32);
#pragma unroll
    for (int q = 0; q < 8; q++)
        dst[q] = make_float4(o[q * 4], o[q * 4 + 1], o[q * 4 + 2], o[q * 4 + 3]);

#pragma unroll
    for (int c = 0; c < 32; c++) {
        float s = o[c], ss = o[c] * o[c];
#pragma unroll
        for (int off = 32; off > 0; off >>= 1) {
            s += __shfl_down(s, off, 64);
            ss += __shfl_down(ss, off, 64);
        }
        if ((threadIdx.x & 63) == 0) {
            atomicAdd(&statv[c * 2], s);
            atomicAdd(&statv[c * 2 + 1], ss);
        }
    }
}

__global__ __launch_bounds__(256) void node_norm_kernel(
    const float* __restrict__ o_v, const float* __restrict__ statv,
    const float* __restrict__ gamma, const float* __restrict__ beta,
    float* __restrict__ dv) {
    const int f = blockIdx.x * 256 + threadIdx.x;
    const int c = f & 31;
    const float M = 8192.0f;
    const float mu = statv[c * 2] / M;
    const float var = statv[c * 2 + 1] / M - mu * mu;
    const float rs = rsqrtf(var + 1e-5f);
    dv[f] = gamma[c] * (o_v[f] - mu) * rs + beta[c];
}

// ---------------------------------------------------------------------------
extern "C" void kernel_launch(void* const* d_in, const int* in_sizes, int n_in,
                              void* d_out, int out_size, void* d_ws, size_t ws_size,
                              hipStream_t stream) {
    const float* v0 = (const float*)d_in[0];
    const float* e0 = (const float*)d_in[1];
    const float* etype = (const float*)d_in[2];
    const float* W1v = (const float*)d_in[3];
    const float* b1v = (const float*)d_in[4];
    const float* W2v = (const float*)d_in[5];
    const float* b2v = (const float*)d_in[6];
    const float* gv = (const float*)d_in[7];
    const float* btv = (const float*)d_in[8];
    const float* W1e = (const float*)d_in[9];
    const float* b1e = (const float*)d_in[10];
    const float* W2e = (const float*)d_in[11];
    const float* b2e = (const float*)d_in[12];
    const float* ge = (const float*)d_in[13];
    const float* bte = (const float*)d_in[14];
    float* out = (float*)d_out;

    // Workspace layout (floats)
    float* ws = (float*)d_ws;
    float* statv = ws;                // 64
    float* buckets = ws + 64;         // 4096
    float* statf = ws + 4160;         // 128
    float* agg = ws + 4288;           // 262144
    float* o_v = ws + 266432;         // 262144

    hipMemsetAsync(statv, 0, (64 + 4096) * sizeof(float), stream);
    hipMemsetAsync(out + DV_SIZE + DE_SIZE, 0, ZERO_SIZE * sizeof(float), stream);

    agg_kernel<<<256, 256, 0, stream>>>(e0, agg);
    node_mlp_kernel<<<32, 256, 0, stream>>>(agg, W1v, b1v, W2v, b2v, o_v, statv);
    node_norm_kernel<<<1024, 256, 0, stream>>>(o_v, statv, gv, btv, out);
    edge_stats_mfma_kernel<<<PBLK, 256, 0, stream>>>(v0, W1e, b1e, W2e, b2e, buckets);
    edge_stats_final_kernel<<<1, 64, 0, stream>>>(buckets, ge, bte, statf);
    edge_out_mfma_kernel<<<PBLK, 256, 0, stream>>>(v0, W1e, b1e, W2e, b2e, statf,
                                                   etype, out + DV_SIZE);
}

// Round 3
// 302.608 us; speedup vs baseline: 1.7453x; 1.2715x over previous
//
#include <hip/hip_runtime.h>

// Problem constants
#define NB 128       // batch (num_sims)
#define NA 64        // num_atoms
#define NE 4032      // edges = NA*(NA-1)
#define KT 2         // edge types
#define BE (NB * NE) // 516096 rows per edge type
#define DV_SIZE 262144
#define DE_SIZE 16515072
#define ZERO_SIZE 1032192

#define TPW 8        // row-tiles (of 16 rows) per wave
#define PBLK 1008    // blocks for edge MFMA passes: 1008*4 waves*8 tiles*16 rows = 516096

typedef __attribute__((ext_vector_type(8))) short short8;
typedef __attribute__((ext_vector_type(4))) float floatx4;

__device__ __forceinline__ float elu(float x) {
    return x > 0.0f ? x : __expf(x) - 1.0f;
}

__device__ __forceinline__ unsigned short f2bf(float x) {
    unsigned u = __float_as_uint(x);
    return (unsigned short)((u + 0x7FFFu + ((u >> 16) & 1u)) >> 16);
}

__device__ __forceinline__ short8 pack8(float4 a, float4 b) {
    short8 r;
    r[0] = (short)f2bf(a.x); r[1] = (short)f2bf(a.y);
    r[2] = (short)f2bf(a.z); r[3] = (short)f2bf(a.w);
    r[4] = (short)f2bf(b.x); r[5] = (short)f2bf(b.y);
    r[6] = (short)f2bf(b.z); r[7] = (short)f2bf(b.w);
    return r;
}

// ===========================================================================
// EDGE PATH (unchanged from R2 — MFMA recompute, no o_e materialization)
// ===========================================================================
struct SM {
    short8 wA1[16][64];            // GEMM1 A-frags: f = ((k*4+mt)*2+kf)   16 KB
    short8 wA2[8][64];             // GEMM2 A-frags: f = ((k*2+mt2)*2+kf)   8 KB
    float b1s[128];
    float b2s[64];
    float afs[64];                 // affine scale (pass B)
    float cfs[64];                 // affine shift (pass B)
    unsigned long long hbuf[4][16 * 20];  // 4 waves x 2560 B
};

__device__ __forceinline__ void stage_weights(SM& sm, const float* __restrict__ W1,
                                              const float* __restrict__ b1,
                                              const float* __restrict__ W2,
                                              const float* __restrict__ b2) {
    const int tid = threadIdx.x;
#pragma unroll
    for (int s = 0; s < 4; s++) {  // 16 frags x 64 lanes
        const int slot = s * 256 + tid;
        const int f = slot >> 6, l = slot & 63;
        const int k = f >> 3, mt = (f >> 1) & 3, kf = f & 1;
        const int g = l >> 4, m15 = l & 15;
        short8 v;
#pragma unroll
        for (int j = 0; j < 8; j++) {
            const int kk = kf * 32 + g * 8 + j;
            v[j] = (short)f2bf(W1[(k * 64 + kk) * 64 + mt * 16 + m15]);
        }
        sm.wA1[f][l] = v;
    }
#pragma unroll
    for (int s = 0; s < 2; s++) {  // 8 frags x 64 lanes
        const int slot = s * 256 + tid;
        const int f = slot >> 6, l = slot & 63;
        const int k = f >> 2, mt2 = (f >> 1) & 1, kf = f & 1;
        const int g = l >> 4, m15 = l & 15;
        short8 v;
#pragma unroll
        for (int j = 0; j < 8; j++) {
            const int kk = kf * 32 + g * 8 + j;
            v[j] = (short)f2bf(W2[(k * 64 + kk) * 32 + mt2 * 16 + m15]);
        }
        sm.wA2[f][l] = v;
    }
    if (tid < 128) sm.b1s[tid] = b1[tid];
    if (tid < 64) sm.b2s[tid] = b2[tid];
}

__device__ __forceinline__ void mlp_tile(const SM& sm, int w, int lane,
                                         const float* __restrict__ v0, int R0,
                                         float o[2][2][4]) {
    const int g = lane >> 4, m15 = lane & 15;
    const int row = R0 + m15;
    const int b = row / NE;
    const int e = row - b * NE;
    const int i = e / 63;
    const int p = e - i * 63;
    const int j = p + (p >= i ? 1 : 0);
    const float4* pr = (const float4*)(v0 + (b * 64 + j) * 32 + g * 8);
    const float4* ps = (const float4*)(v0 + (b * 64 + i) * 32 + g * 8);
    const short8 bx0 = pack8(pr[0], pr[1]);
    const short8 bx1 = pack8(ps[0], ps[1]);

    const char* hbase = (const char*)&sm.hbuf[w][0];
    unsigned long long* hw = const_cast<unsigned long long*>(&sm.hbuf[w][0]);

#pragma unroll
    for (int k = 0; k < 2; k++) {
#pragma unroll
        for (int mt = 0; mt < 4; mt++) {
            floatx4 acc = {0.f, 0.f, 0.f, 0.f};
            acc = __builtin_amdgcn_mfma_f32_16x16x32_bf16(sm.wA1[(k * 4 + mt) * 2 + 0][lane], bx0, acc, 0, 0, 0);
            acc = __builtin_amdgcn_mfma_f32_16x16x32_bf16(sm.wA1[(k * 4 + mt) * 2 + 1][lane], bx1, acc, 0, 0, 0);
            const float4 bb = *(const float4*)&sm.b1s[k * 64 + mt * 16 + 4 * g];
            const unsigned lo = (unsigned)f2bf(elu(acc[0] + bb.x)) |
                                ((unsigned)f2bf(elu(acc[1] + bb.y)) << 16);
            const unsigned hi = (unsigned)f2bf(elu(acc[2] + bb.z)) |
                                ((unsigned)f2bf(elu(acc[3] + bb.w)) << 16);
            hw[m15 * 20 + mt * 4 + g] = ((unsigned long long)hi << 32) | lo;
        }
        const short8 bh0 = *(const short8*)(hbase + m15 * 160 + 0 + g * 16);
        const short8 bh1 = *(const short8*)(hbase + m15 * 160 + 64 + g * 16);
#pragma unroll
        for (int mt2 = 0; mt2 < 2; mt2++) {
            floatx4 acc = {0.f, 0.f, 0.f, 0.f};
            acc = __builtin_amdgcn_mfma_f32_16x16x32_bf16(sm.wA2[(k * 2 + mt2) * 2 + 0][lane], bh0, acc, 0, 0, 0);
            acc = __builtin_amdgcn_mfma_f32_16x16x32_bf16(sm.wA2[(k * 2 + mt2) * 2 + 1][lane], bh1, acc, 0, 0, 0);
            const float4 bb = *(const float4*)&sm.b2s[k * 32 + mt2 * 16 + 4 * g];
            o[k][mt2][0] = elu(acc[0] + bb.x);
            o[k][mt2][1] = elu(acc[1] + bb.y);
            o[k][mt2][2] = elu(acc[2] + bb.z);
            o[k][mt2][3] = elu(acc[3] + bb.w);
        }
    }
}

__global__ __launch_bounds__(256) void edge_stats_mfma_kernel(
    const float* __restrict__ v0, const float* __restrict__ W1,
    const float* __restrict__ b1, const float* __restrict__ W2,
    const float* __restrict__ b2, float* __restrict__ buckets) {
    __shared__ SM sm;
    stage_weights(sm, W1, b1, W2, b2);
    __syncthreads();

    const int lane = threadIdx.x & 63;
    const int w = threadIdx.x >> 6;
    const int g = lane >> 4, m15 = lane & 15;
    const int gw = blockIdx.x * 4 + w;

    float st[2][2][4], sq[2][2][4];
#pragma unroll
    for (int k = 0; k < 2; k++)
#pragma unroll
        for (int m = 0; m < 2; m++)
#pragma unroll
            for (int r = 0; r < 4; r++) { st[k][m][r] = 0.f; sq[k][m][r] = 0.f; }

#pragma unroll 1
    for (int tt = 0; tt < TPW; tt++) {
        const int R0 = (gw * TPW + tt) * 16;
        float o[2][2][4];
        mlp_tile(sm, w, lane, v0, R0, o);
#pragma unroll
        for (int k = 0; k < 2; k++)
#pragma unroll
            for (int m = 0; m < 2; m++)
#pragma unroll
                for (int r = 0; r < 4; r++) {
                    const float v = o[k][m][r];
                    st[k][m][r] += v;
                    sq[k][m][r] += v * v;
                }
    }

    const int bk = gw & 31;
#pragma unroll
    for (int k = 0; k < 2; k++)
#pragma unroll
        for (int m = 0; m < 2; m++)
#pragma unroll
            for (int r = 0; r < 4; r++) {
                float s = st[k][m][r], ss = sq[k][m][r];
#pragma unroll
                for (int off = 1; off < 16; off <<= 1) {
                    s += __shfl_xor(s, off, 64);
                    ss += __shfl_xor(ss, off, 64);
                }
                if (m15 == 0) {
                    const int ch = m * 16 + 4 * g + r;
                    atomicAdd(&buckets[((bk * KT + k) * 32 + ch) * 2], s);
                    atomicAdd(&buckets[((bk * KT + k) * 32 + ch) * 2 + 1], ss);
                }
            }
}

__global__ void edge_stats_final_kernel(const float* __restrict__ buckets,
                                        const float* __restrict__ gamma,
                                        const float* __restrict__ beta,
                                        float* __restrict__ statf) {
    const int t = threadIdx.x;
    if (t >= 64) return;
    const int k = t >> 5, c = t & 31;
    float s = 0.0f, ss = 0.0f;
#pragma unroll 1
    for (int bk = 0; bk < 32; bk++) {
        s += buckets[((bk * KT + k) * 32 + c) * 2];
        ss += buckets[((bk * KT + k) * 32 + c) * 2 + 1];
    }
    const float M = (float)BE;
    const float mu = s / M;
    const float var = ss / M - mu * mu;
    const float rs = rsqrtf(var + 1e-5f);
    const float af = gamma[k * 32 + c] * rs;
    statf[t * 2] = af;
    statf[t * 2 + 1] = beta[k * 32 + c] - mu * af;
}

__global__ __launch_bounds__(256) void edge_out_mfma_kernel(
    const float* __restrict__ v0, const float* __restrict__ W1,
    const float* __restrict__ b1, const float* __restrict__ W2,
    const float* __restrict__ b2, const float* __restrict__ statf,
    const float* __restrict__ etype, float* __restrict__ de) {
    __shared__ SM sm;
    stage_weights(sm, W1, b1, W2, b2);
    if (threadIdx.x < 64) {
        sm.afs[threadIdx.x] = statf[threadIdx.x * 2];
        sm.cfs[threadIdx.x] = statf[threadIdx.x * 2 + 1];
    }
    __syncthreads();

    const int lane = threadIdx.x & 63;
    const int w = threadIdx.x >> 6;
    const int g = lane >> 4, m15 = lane & 15;
    const int gw = blockIdx.x * 4 + w;

#pragma unroll 1
    for (int tt = 0; tt < TPW; tt++) {
        const int R0 = (gw * TPW + tt) * 16;
        float o[2][2][4];
        mlp_tile(sm, w, lane, v0, R0, o);
        const int row = R0 + m15;
        const float w0 = etype[row * 2 + 0];
        const float w1 = etype[row * 2 + 1];
#pragma unroll
        for (int mt2 = 0; mt2 < 2; mt2++) {
            const float4 a0 = *(const float4*)&sm.afs[mt2 * 16 + 4 * g];
            const float4 c0 = *(const float4*)&sm.cfs[mt2 * 16 + 4 * g];
            const float4 a1 = *(const float4*)&sm.afs[32 + mt2 * 16 + 4 * g];
            const float4 c1 = *(const float4*)&sm.cfs[32 + mt2 * 16 + 4 * g];
            float4 r;
            r.x = w0 * (a0.x * o[0][mt2][0] + c0.x) + w1 * (a1.x * o[1][mt2][0] + c1.x);
            r.y = w0 * (a0.y * o[0][mt2][1] + c0.y) + w1 * (a1.y * o[1][mt2][1] + c1.y);
            r.z = w0 * (a0.z * o[0][mt2][2] + c0.z) + w1 * (a1.z * o[1][mt2][2] + c1.z);
            r.w = w0 * (a0.w * o[0][mt2][3] + c0.w) + w1 * (a1.w * o[1][mt2][3] + c1.w);
            *(float4*)(de + (size_t)row * 32 + mt2 * 16 + 4 * g) = r;
        }
    }
}

// ===========================================================================
// AGG: agg[b,j,c4] = (1/64) * sum_{i != j} e0[b, i, pos(i,j), c4]
// ===========================================================================
__global__ __launch_bounds__(256) void agg_kernel(const float* __restrict__ e0,
                                                  float* __restrict__ agg) {
    const int f = blockIdx.x * 256 + threadIdx.x;  // 65536 = B*N*8
    const int c4 = f & 7;
    const int jn = (f >> 3) & 63;
    const int b = f >> 9;
    const float4* base = (const float4*)e0 + (size_t)b * 64 * 63 * 8;
    float x = 0.f, y = 0.f, z = 0.f, ww = 0.f;
#pragma unroll 1
    for (int i = 0; i < 64; i++) {
        if (i == jn) continue;
        const int p = jn - (jn > i ? 1 : 0);
        const float4 v = base[(i * 63 + p) * 8 + c4];
        x += v.x; y += v.y; z += v.z; ww += v.w;
    }
    const float s = 1.0f / 64.0f;
    *(float4*)(agg + (size_t)f * 4) = make_float4(x * s, y * s, z * s, ww * s);
}

// ===========================================================================
// NODE PATH — MFMA version (replaces the spilling scalar node_mlp_kernel).
// X = agg [8192][32], W1v (32,64), W2v (64,32). Transposed compute so the
// MFMA C-layout keeps rows in lane&15 (same machinery as the edge path).
// ===========================================================================
struct SMN {
    short8 wA1n[4][64];            // GEMM1 A-frags, f = mt (K=32: single kf)  4 KB
    short8 wA2n[4][64];            // GEMM2 A-frags, f = mt2*2+kf              4 KB
    float b1s[64];
    float b2s[32];
    unsigned long long hbuf[4][16 * 20];
};

__global__ __launch_bounds__(256) void node_mlp_mfma_kernel(
    const float* __restrict__ agg, const float* __restrict__ W1,
    const float* __restrict__ b1, const float* __restrict__ W2,
    const float* __restrict__ b2, float* __restrict__ o_v,
    float* __restrict__ nbuckets) {
    __shared__ SMN sm;
    const int tid = threadIdx.x;
    {   // stage W1^T frags: A[m15][k=g*8+j] = W1[(g*8+j)*64 + mt*16 + m15]
        const int f = tid >> 6, l = tid & 63;
        const int g = l >> 4, m15 = l & 15;
        short8 v;
#pragma unroll
        for (int j = 0; j < 8; j++)
            v[j] = (short)f2bf(W1[(g * 8 + j) * 64 + f * 16 + m15]);
        sm.wA1n[f][l] = v;
        // stage W2^T frags: f2 = mt2*2+kf; A[m15][kf*32+g*8+j] = W2[(kf*32+g*8+j)*32 + mt2*16+m15]
        const int mt2 = f >> 1, kf = f & 1;
        short8 u;
#pragma unroll
        for (int j = 0; j < 8; j++)
            u[j] = (short)f2bf(W2[(kf * 32 + g * 8 + j) * 32 + mt2 * 16 + m15]);
        sm.wA2n[f][l] = u;
    }
    if (tid < 64) sm.b1s[tid] = b1[tid];
    else if (tid < 96) sm.b2s[tid - 64] = b2[tid - 64];
    __syncthreads();

    const int lane = tid & 63;
    const int w = tid >> 6;
    const int g = lane >> 4, m15 = lane & 15;
    const int tile = blockIdx.x * 4 + w;     // 512 tiles
    const int R0 = tile * 16;
    const int row = R0 + m15;

    // B-frag: lane holds row=m15's 32 input channels (k = g*8+j)
    const float4* px = (const float4*)(agg + (size_t)row * 32 + g * 8);
    const short8 bx = pack8(px[0], px[1]);

    const char* hbase = (const char*)&sm.hbuf[w][0];
    unsigned long long* hw = &sm.hbuf[w][0];

#pragma unroll
    for (int mt = 0; mt < 4; mt++) {
        floatx4 acc = {0.f, 0.f, 0.f, 0.f};
        acc = __builtin_amdgcn_mfma_f32_16x16x32_bf16(sm.wA1n[mt][lane], bx, acc, 0, 0, 0);
        const float4 bb = *(const float4*)&sm.b1s[mt * 16 + 4 * g];
        const unsigned lo = (unsigned)f2bf(elu(acc[0] + bb.x)) |
                            ((unsigned)f2bf(elu(acc[1] + bb.y)) << 16);
        const unsigned hi = (unsigned)f2bf(elu(acc[2] + bb.z)) |
                            ((unsigned)f2bf(elu(acc[3] + bb.w)) << 16);
        hw[m15 * 20 + mt * 4 + g] = ((unsigned long long)hi << 32) | lo;
    }
    const short8 bh0 = *(const short8*)(hbase + m15 * 160 + 0 + g * 16);
    const short8 bh1 = *(const short8*)(hbase + m15 * 160 + 64 + g * 16);

    const int bk = tile & 31;
#pragma unroll
    for (int mt2 = 0; mt2 < 2; mt2++) {
        floatx4 acc = {0.f, 0.f, 0.f, 0.f};
        acc = __builtin_amdgcn_mfma_f32_16x16x32_bf16(sm.wA2n[mt2 * 2 + 0][lane], bh0, acc, 0, 0, 0);
        acc = __builtin_amdgcn_mfma_f32_16x16x32_bf16(sm.wA2n[mt2 * 2 + 1][lane], bh1, acc, 0, 0, 0);
        const float4 bb = *(const float4*)&sm.b2s[mt2 * 16 + 4 * g];
        float4 ov;
        ov.x = elu(acc[0] + bb.x);
        ov.y = elu(acc[1] + bb.y);
        ov.z = elu(acc[2] + bb.z);
        ov.w = elu(acc[3] + bb.w);
        *(float4*)(o_v + (size_t)row * 32 + mt2 * 16 + 4 * g) = ov;
        // BN stats: reduce over the 16 row-lanes, atomics from m15==0
        const float vv[4] = {ov.x, ov.y, ov.z, ov.w};
#pragma unroll
        for (int r = 0; r < 4; r++) {
            float s = vv[r], ss = vv[r] * vv[r];
#pragma unroll
            for (int off = 1; off < 16; off <<= 1) {
                s += __shfl_xor(s, off, 64);
                ss += __shfl_xor(ss, off, 64);
            }
            if (m15 == 0) {
                const int ch = mt2 * 16 + 4 * g + r;
                atomicAdd(&nbuckets[(bk * 32 + ch) * 2], s);
                atomicAdd(&nbuckets[(bk * 32 + ch) * 2 + 1], ss);
            }
        }
    }
}

__global__ void node_stats_final_kernel(const float* __restrict__ nbuckets,
                                        const float* __restrict__ gamma,
                                        const float* __restrict__ beta,
                                        float* __restrict__ statn) {
    const int c = threadIdx.x;
    if (c >= 32) return;
    float s = 0.0f, ss = 0.0f;
#pragma unroll 1
    for (int bk = 0; bk < 32; bk++) {
        s += nbuckets[(bk * 32 + c) * 2];
        ss += nbuckets[(bk * 32 + c) * 2 + 1];
    }
    const float M = 8192.0f;
    const float mu = s / M;
    const float var = ss / M - mu * mu;
    const float rs = rsqrtf(var + 1e-5f);
    const float af = gamma[c] * rs;
    statn[c * 2] = af;
    statn[c * 2 + 1] = beta[c] - mu * af;
}

__global__ __launch_bounds__(256) void node_norm_kernel(
    const float* __restrict__ o_v, const float* __restrict__ statn,
    float* __restrict__ dv) {
    const int f = blockIdx.x * 256 + threadIdx.x;
    const int c = f & 31;
    dv[f] = statn[c * 2] * o_v[f] + statn[c * 2 + 1];
}

// ---------------------------------------------------------------------------
extern "C" void kernel_launch(void* const* d_in, const int* in_sizes, int n_in,
                              void* d_out, int out_size, void* d_ws, size_t ws_size,
                              hipStream_t stream) {
    const float* v0 = (const float*)d_in[0];
    const float* e0 = (const float*)d_in[1];
    const float* etype = (const float*)d_in[2];
    const float* W1v = (const float*)d_in[3];
    const float* b1v = (const float*)d_in[4];
    const float* W2v = (const float*)d_in[5];
    const float* b2v = (const float*)d_in[6];
    const float* gv = (const float*)d_in[7];
    const float* btv = (const float*)d_in[8];
    const float* W1e = (const float*)d_in[9];
    const float* b1e = (const float*)d_in[10];
    const float* W2e = (const float*)d_in[11];
    const float* b2e = (const float*)d_in[12];
    const float* ge = (const float*)d_in[13];
    const float* bte = (const float*)d_in[14];
    float* out = (float*)d_out;

    // Workspace layout (floats)
    float* ws = (float*)d_ws;
    float* buckets = ws;              // 4096  (edge BN buckets)
    float* statf = ws + 4096;         // 128
    float* nbuckets = ws + 4224;      // 2048  (node BN buckets)
    float* statn = ws + 6272;         // 64
    float* agg = ws + 6336;           // 262144
    float* o_v = ws + 268480;         // 262144

    hipMemsetAsync(buckets, 0, (4096 + 128 + 2048) * sizeof(float), stream);
    hipMemsetAsync(out + DV_SIZE + DE_SIZE, 0, ZERO_SIZE * sizeof(float), stream);

    agg_kernel<<<256, 256, 0, stream>>>(e0, agg);
    node_mlp_mfma_kernel<<<128, 256, 0, stream>>>(agg, W1v, b1v, W2v, b2v, o_v, nbuckets);
    node_stats_final_kernel<<<1, 64, 0, stream>>>(nbuckets, gv, btv, statn);
    node_norm_kernel<<<1024, 256, 0, stream>>>(o_v, statn, out);
    edge_stats_mfma_kernel<<<PBLK, 256, 0, stream>>>(v0, W1e, b1e, W2e, b2e, buckets);
    edge_stats_final_kernel<<<1, 64, 0, stream>>>(buckets, ge, bte, statf);
    edge_out_mfma_kernel<<<PBLK, 256, 0, stream>>>(v0, W1e, b1e, W2e, b2e, statf,
                                                   etype, out + DV_SIZE);
}